// Round 1
// baseline (921.453 us; speedup 1.0000x reference)
//
#include <hip/hip_runtime.h>
#include <math.h>
#include <cstdint>
#include <cstddef>

#define Bn   1024
#define Gn   2048
#define Pn   256
#define GHn  128
#define EHn  64
#define EOn  16
#define CHn  8
#define KSEL 3
#define KSPLIT 8
#define BN_EPS 1e-5f

// ---------------- K0: zero acc + counts ----------------
__global__ void k0_init(float* __restrict__ acc, int* __restrict__ counts) {
    int t = blockIdx.x * 256 + threadIdx.x;
    if (t < Bn * EOn) acc[t] = 0.f;
    if (t < Pn) counts[t] = 0;
}

// ---------------- K1: gh_part[s] = x_rna @ gate_W1 (K-split partials) ----------------
__global__ __launch_bounds__(256) void k1_gemm1(const float* __restrict__ x,
                                                const float* __restrict__ W1,
                                                float* __restrict__ gh_part) {
    __shared__ float xs[32][65];       // 32 rows x 64 k (+pad)
    __shared__ float ws_[64][GHn];     // 64 k x 128 cols
    const int tid = threadIdx.x;
    const int rt  = blockIdx.x * 32;         // row tile base
    const int k0  = blockIdx.y * (Gn / KSPLIT); // 256-wide K split
    const int c   = (tid & 31) * 4;          // col base (0..124)
    const int rb  = (tid >> 5) * 4;          // row base within tile (0..28)
    float acc[4][4] = {};
    for (int kc = 0; kc < 4; ++kc) {         // 4 sub-chunks of 64
        const int kb = k0 + kc * 64;
        #pragma unroll
        for (int i = 0; i < 8; ++i) {        // stage x: 32x64
            int idx = i * 256 + tid; int r = idx >> 6, kk = idx & 63;
            xs[r][kk] = x[(size_t)(rt + r) * Gn + kb + kk];
        }
        #pragma unroll
        for (int i = 0; i < 32; ++i) {       // stage W1: 64x128
            int idx = i * 256 + tid; int k = idx >> 7, cc = idx & 127;
            ws_[k][cc] = W1[(size_t)(kb + k) * GHn + cc];
        }
        __syncthreads();
        #pragma unroll 8
        for (int kk = 0; kk < 64; ++kk) {
            float4 wv = *reinterpret_cast<const float4*>(&ws_[kk][c]);
            #pragma unroll
            for (int i = 0; i < 4; ++i) {
                float xv = xs[rb + i][kk];
                acc[i][0] += xv * wv.x; acc[i][1] += xv * wv.y;
                acc[i][2] += xv * wv.z; acc[i][3] += xv * wv.w;
            }
        }
        __syncthreads();
    }
    float* gp = gh_part + (size_t)blockIdx.y * Bn * GHn;
    #pragma unroll
    for (int i = 0; i < 4; ++i) {
        float4 v = { acc[i][0], acc[i][1], acc[i][2], acc[i][3] };
        *reinterpret_cast<float4*>(&gp[(size_t)(rt + rb + i) * GHn + c]) = v;
    }
}

// ---------------- K2: gate logits + top-3 + sigmoid + gate_weights + counts ----------------
__global__ __launch_bounds__(256) void k2_gate(const float* __restrict__ gh_part,
                                               const float* __restrict__ b1,
                                               const float* __restrict__ W2,
                                               const float* __restrict__ b2,
                                               float* __restrict__ gw_out,
                                               int* __restrict__ topk_idx,
                                               float* __restrict__ topk_w,
                                               int* __restrict__ counts) {
    __shared__ float ghs[8][GHn];
    const int tid = threadIdx.x, wv = tid >> 6, l = tid & 63;
    const int r0 = blockIdx.x * 8 + wv * 2;   // wave handles rows r0, r0+1
    // stage relu(sum of partials + b1)
    for (int rr = 0; rr < 2; ++rr) {
        int row = r0 + rr;
        for (int e = l; e < GHn; e += 64) {
            float s = b1[e];
            #pragma unroll
            for (int p8 = 0; p8 < KSPLIT; ++p8)
                s += gh_part[((size_t)p8 * Bn + row) * GHn + e];
            ghs[wv * 2 + rr][e] = fmaxf(s, 0.f);
        }
    }
    // wave-local LDS write->read; compiler inserts lgkmcnt waits
    float a0[4] = {}, a1[4] = {};
    for (int k = 0; k < GHn; ++k) {
        float g0 = ghs[wv * 2][k], g1 = ghs[wv * 2 + 1][k];
        #pragma unroll
        for (int j = 0; j < 4; ++j) {
            float w = W2[(size_t)k * Pn + j * 64 + l];
            a0[j] += g0 * w; a1[j] += g1 * w;
        }
    }
    #pragma unroll
    for (int j = 0; j < 4; ++j) { float bb = b2[j * 64 + l]; a0[j] += bb; a1[j] += bb; }

    for (int rr = 0; rr < 2; ++rr) {
        int row = r0 + rr;
        float v[4];
        #pragma unroll
        for (int j = 0; j < 4; ++j) v[j] = rr ? a1[j] : a0[j];
        float topv[3]; int topi[3];
        for (int round = 0; round < 3; ++round) {
            float bv = v[0]; int bi = l;             // col for j=0 is l
            #pragma unroll
            for (int j = 1; j < 4; ++j) {            // cols ascend with j: strict > keeps lowest idx
                if (v[j] > bv) { bv = v[j]; bi = j * 64 + l; }
            }
            #pragma unroll
            for (int m = 32; m >= 1; m >>= 1) {      // butterfly argmax, tie -> lower index
                float ov = __shfl_xor(bv, m); int oi = __shfl_xor(bi, m);
                if (ov > bv || (ov == bv && oi < bi)) { bv = ov; bi = oi; }
            }
            topv[round] = bv; topi[round] = bi;
            if ((bi & 63) == l) v[bi >> 6] = -1e30f; // mask winner
        }
        float wg[3];
        #pragma unroll
        for (int r3 = 0; r3 < 3; ++r3) wg[r3] = 1.f / (1.f + expf(-topv[r3]));
        #pragma unroll
        for (int j = 0; j < 4; ++j) {
            int col = j * 64 + l; float o = 0.f;
            #pragma unroll
            for (int r3 = 0; r3 < 3; ++r3) if (col == topi[r3]) o = wg[r3];
            gw_out[(size_t)row * Pn + col] = o;
        }
        if (l < KSEL) {
            topk_idx[row * KSEL + l] = topi[l];
            topk_w[row * KSEL + l]  = wg[l];
            atomicAdd(&counts[topi[l]], 1);
        }
    }
}

// ---------------- K3: exclusive scan of counts -> offsets; zero cursors ----------------
__global__ void k3_scan(const int* __restrict__ counts, int* __restrict__ offsets,
                        int* __restrict__ cursors) {
    __shared__ int s[Pn];
    int tid = threadIdx.x;
    int c = counts[tid];
    s[tid] = c; __syncthreads();
    for (int off = 1; off < Pn; off <<= 1) {
        int v = (tid >= off) ? s[tid - off] : 0;
        __syncthreads();
        s[tid] += v;
        __syncthreads();
    }
    offsets[tid] = s[tid] - c;
    if (tid == Pn - 1) offsets[Pn] = s[Pn - 1];
    cursors[tid] = 0;
}

// ---------------- K4: scatter (b, w) into per-pathway lists ----------------
__global__ void k4_scatter(const int* __restrict__ topk_idx, const float* __restrict__ topk_w,
                           const int* __restrict__ offsets, int* __restrict__ cursors,
                           int* __restrict__ rowlist, float* __restrict__ wlist) {
    int t = blockIdx.x * 256 + threadIdx.x;
    if (t >= Bn * KSEL) return;
    int p = topk_idx[t];
    int pos = offsets[p] + atomicAdd(&cursors[p], 1);
    rowlist[pos] = t / KSEL;
    wlist[pos]  = topk_w[t];
}

// ---------------- K5: sparse experts, grouped by pathway ----------------
__global__ __launch_bounds__(256) void k5_experts(
        const float* __restrict__ x_rna, const float* __restrict__ x_cnv,
        const float* __restrict__ x_met, const float* __restrict__ gene_mask,
        const float* __restrict__ eW1,  const float* __restrict__ eb1,
        const float* __restrict__ bn_g, const float* __restrict__ bn_b,
        const float* __restrict__ bn_m, const float* __restrict__ bn_v,
        const float* __restrict__ eW2,  const float* __restrict__ eb2,
        const int* __restrict__ offsets, const int* __restrict__ rowlist,
        const float* __restrict__ wlist, float* __restrict__ acc) {
    __shared__ int   glist[Gn];
    __shared__ int   ng_s;
    __shared__ float w2s[EHn * EOn];
    __shared__ float eb2s[EOn];
    __shared__ float scs[EHn], shs[EHn];
    __shared__ float hA[4][EHn], hB[4][EHn];
    const int p   = blockIdx.x;
    const int sub = blockIdx.y;            // 2 blocks per pathway split the rows
    const int wv  = threadIdx.x >> 6, l = threadIdx.x & 63;

    if (wv == 0) {                         // ordered mask-column compaction (one wave)
        int base = 0;
        for (int i = 0; i < Gn / 64; ++i) {
            int g = i * 64 + l;
            bool nz = gene_mask[(size_t)g * Pn + p] != 0.f;
            unsigned long long m = __ballot(nz);
            if (nz) glist[base + __popcll(m & ((1ull << l) - 1ull))] = g;
            base += __popcll(m);
        }
        if (l == 0) ng_s = base;
    } else if (wv == 1) {                  // folded BN scale/shift
        float gmm = bn_g[p * EHn + l], btt = bn_b[p * EHn + l];
        float mnn = bn_m[p * EHn + l], vrr = bn_v[p * EHn + l];
        float s = gmm / sqrtf(vrr + BN_EPS);
        scs[l] = s; shs[l] = btt - mnn * s;
    } else if (wv == 2) {
        for (int i = l; i < EHn * EOn; i += 64) w2s[i] = eW2[(size_t)p * EHn * EOn + i];
    } else {
        if (l < EOn) eb2s[l] = eb2[p * EOn + l];
    }
    __syncthreads();

    const int off = offsets[p], nrows = offsets[p + 1] - off;
    const int ng = ng_s;
    const float eb1e = eb1[p * EHn + l];
    const float* W1p = eW1 + (size_t)p * (3 * Gn) * EHn;
    const int gwv = sub * 4 + wv;          // 0..7 global wave id for this pathway

    for (int ridx = gwv * 2; ridx < nrows; ridx += 16) {
        int b0 = rowlist[off + ridx];
        bool has1 = (ridx + 1) < nrows;
        int b1r = has1 ? rowlist[off + ridx + 1] : b0;
        float wt0 = wlist[off + ridx];
        float wt1 = has1 ? wlist[off + ridx + 1] : 0.f;
        const float* xr0 = x_rna + (size_t)b0 * Gn;
        const float* xc0 = x_cnv + (size_t)b0 * Gn;
        const float* xm0 = x_met + (size_t)b0 * Gn;
        const float* xr1 = x_rna + (size_t)b1r * Gn;
        const float* xc1 = x_cnv + (size_t)b1r * Gn;
        const float* xm1 = x_met + (size_t)b1r * Gn;
        // 3 split accumulators per row break the FMA dependency chain
        float hx0 = eb1e, hy0 = 0.f, hz0 = 0.f;
        float hx1 = eb1e, hy1 = 0.f, hz1 = 0.f;
        for (int gi = 0; gi < ng; ++gi) {
            int g = glist[gi];
            float wA = W1p[(size_t)g * EHn + l];                 // omic 0 row
            float wB = W1p[((size_t)Gn + g) * EHn + l];          // omic 1 row
            float wC = W1p[((size_t)2 * Gn + g) * EHn + l];      // omic 2 row
            hx0 += xr0[g] * wA; hy0 += xc0[g] * wB; hz0 += xm0[g] * wC;
            hx1 += xr1[g] * wA; hy1 += xc1[g] * wB; hz1 += xm1[g] * wC;
        }
        float h0 = fmaxf(0.f, (hx0 + hy0 + hz0) * scs[l] + shs[l]);
        float h1 = fmaxf(0.f, (hx1 + hy1 + hz1) * scs[l] + shs[l]);
        hA[wv][l] = h0; hB[wv][l] = h1;
        if (l < EOn) {
            float f0 = eb2s[l], f1 = eb2s[l];
            for (int e = 0; e < EHn; ++e) {
                f0 += hA[wv][e] * w2s[e * EOn + l];
                f1 += hB[wv][e] * w2s[e * EOn + l];
            }
            atomicAdd(&acc[(size_t)b0 * EOn + l], wt0 * f0);
            if (has1) atomicAdd(&acc[(size_t)b1r * EOn + l], wt1 * f1);
        }
    }
}

// ---------------- K6: classifier ----------------
__global__ void k6_cls(const float* __restrict__ acc, const float* __restrict__ cW1,
                       const float* __restrict__ cb1, const float* __restrict__ cW2,
                       const float* __restrict__ cb2, float* __restrict__ out) {
    int t = blockIdx.x * 256 + threadIdx.x;
    if (t >= Bn) return;
    float a[EOn];
    #pragma unroll
    for (int o = 0; o < EOn; ++o) a[o] = acc[(size_t)t * EOn + o];
    float lg = cb2[0];
    #pragma unroll
    for (int j = 0; j < CHn; ++j) {
        float h = cb1[j];
        #pragma unroll
        for (int o = 0; o < EOn; ++o) h += a[o] * cW1[o * CHn + j];
        lg += fmaxf(h, 0.f) * cW2[j];
    }
    out[t] = lg;
}

extern "C" void kernel_launch(void* const* d_in, const int* in_sizes, int n_in,
                              void* d_out, int out_size, void* d_ws, size_t ws_size,
                              hipStream_t stream) {
    const float* x_rna     = (const float*)d_in[0];
    const float* x_cnv     = (const float*)d_in[1];
    const float* x_met     = (const float*)d_in[2];
    const float* gene_mask = (const float*)d_in[3];
    const float* gate_W1   = (const float*)d_in[4];
    const float* gate_b1   = (const float*)d_in[5];
    const float* gate_W2   = (const float*)d_in[6];
    const float* gate_b2   = (const float*)d_in[7];
    const float* eW1       = (const float*)d_in[8];
    const float* eb1       = (const float*)d_in[9];
    const float* bn_g      = (const float*)d_in[10];
    const float* bn_b      = (const float*)d_in[11];
    const float* bn_m      = (const float*)d_in[12];
    const float* bn_v      = (const float*)d_in[13];
    const float* eW2       = (const float*)d_in[14];
    const float* eb2       = (const float*)d_in[15];
    const float* cW1       = (const float*)d_in[16];
    const float* cb1       = (const float*)d_in[17];
    const float* cW2       = (const float*)d_in[18];
    const float* cb2       = (const float*)d_in[19];

    float* out_logits = (float*)d_out;
    float* out_gw     = out_logits + Bn;   // [B, P] follows [B, NC=1]

    char* ws = (char*)d_ws;
    float* gh_part  = (float*)ws; ws += sizeof(float) * KSPLIT * Bn * GHn;   // 4 MB
    float* accw     = (float*)ws; ws += sizeof(float) * Bn * EOn;
    int*   topk_idx = (int*)ws;   ws += sizeof(int) * Bn * KSEL;
    float* topk_w   = (float*)ws; ws += sizeof(float) * Bn * KSEL;
    int*   counts   = (int*)ws;   ws += sizeof(int) * Pn;
    int*   offsets  = (int*)ws;   ws += sizeof(int) * (Pn + 1);
    int*   cursors  = (int*)ws;   ws += sizeof(int) * Pn;
    int*   rowlist  = (int*)ws;   ws += sizeof(int) * Bn * KSEL;
    float* wlist    = (float*)ws; ws += sizeof(float) * Bn * KSEL;

    hipLaunchKernelGGL(k0_init,    dim3(64),      dim3(256), 0, stream, accw, counts);
    hipLaunchKernelGGL(k1_gemm1,   dim3(32, 8),   dim3(256), 0, stream, x_rna, gate_W1, gh_part);
    hipLaunchKernelGGL(k2_gate,    dim3(128),     dim3(256), 0, stream, gh_part, gate_b1,
                       gate_W2, gate_b2, out_gw, topk_idx, topk_w, counts);
    hipLaunchKernelGGL(k3_scan,    dim3(1),       dim3(256), 0, stream, counts, offsets, cursors);
    hipLaunchKernelGGL(k4_scatter, dim3(12),      dim3(256), 0, stream, topk_idx, topk_w,
                       offsets, cursors, rowlist, wlist);
    hipLaunchKernelGGL(k5_experts, dim3(256, 2),  dim3(256), 0, stream, x_rna, x_cnv, x_met,
                       gene_mask, eW1, eb1, bn_g, bn_b, bn_m, bn_v, eW2, eb2,
                       offsets, rowlist, wlist, accw);
    hipLaunchKernelGGL(k6_cls,     dim3(4),       dim3(256), 0, stream, accw, cW1, cb1,
                       cW2, cb2, out_logits);
}